// Round 1
// baseline (1454.920 us; speedup 1.0000x reference)
//
#include <hip/hip_runtime.h>

// Problem constants
#define TT     2048   // SEQ
#define NBATCH 32     // BATCH
#define NS     512    // N_STATE
#define MM     64     // M_IN
#define PP     64     // P_OUT
#define BLK    64     // tau-block
#define NBLK   32     // TT/BLK
#define CHUNK  128    // i-chunk width held in LDS
#define NCHUNK 4      // NS/CHUNK

// ---------------------------------------------------------------------------
// q_j[p] = sum_{i=j}^{NS-1} C[p,i] * a[NS-1-i+j]   (feedback->output taps)
// ---------------------------------------------------------------------------
__global__ void __launch_bounds__(64) kq_kernel(const float* __restrict__ Cm,
                                                const float* __restrict__ a,
                                                float* __restrict__ q) {
    const int j = blockIdx.x;
    const int p = threadIdx.x;
    float acc = 0.f;
    for (int i = j; i < NS; ++i) acc += Cm[p * NS + i] * a[NS - 1 - i + j];
    q[j * PP + p] = acc;
}

// ---------------------------------------------------------------------------
// Tile kernel. One WG per (tau-block, batch). Computes Bu tile (64 x NS) in
// i-chunks of 128 inside LDS, then walks diagonals (i - tau = const).
// FULL=0: emit per-block diagonal sums S (block-carry inputs).
// FULL=1: full diagonal cumsum with carry R -> G tile; y_part = C*G + D*u;
//         emit f[t] = G_t[NS-1].
// ---------------------------------------------------------------------------
template <int FULL>
__global__ void __launch_bounds__(256) tile_kernel(
    const float* __restrict__ u, const float* __restrict__ B,
    const float* __restrict__ Cm, const float* __restrict__ Dm,
    const float* __restrict__ Rbuf, float* __restrict__ Sbuf,
    float* __restrict__ fbuf, float* __restrict__ y) {
    __shared__ float u_lds[BLK][MM];       // 16 KB
    __shared__ float gbuf[BLK][CHUNK];     // 32 KB
    __shared__ float colBuf[2][BLK];       // diagonal carry across i-chunks

    const int blk = blockIdx.x, b = blockIdx.y;
    const int t0  = blk * BLK;
    const int tid = threadIdx.x;

    // load u tile (64 x 64 floats) coalesced
    {
        const float4* usrc = (const float4*)(u + ((size_t)b * TT + t0) * MM);
        float4* udst = (float4*)(&u_lds[0][0]);
#pragma unroll
        for (int k = 0; k < 4; ++k) udst[tid + 256 * k] = usrc[tid + 256 * k];
    }
    if (tid < BLK) colBuf[0][tid] = 0.f;
    __syncthreads();

    float yacc[16];
    if (FULL) {
#pragma unroll
        for (int k = 0; k < 16; ++k) yacc[k] = 0.f;
    }

    int cur = 0;
    for (int ch = 0; ch < NCHUNK; ++ch) {
        // ---- Bu chunk GEMM: gbuf[dt][il] = B[gi,:] . u[t0+dt,:] ----
        {
            const int il   = tid & (CHUNK - 1);  // 0..127 (fixed B row)
            const int dt0g = tid >> 7;           // 0 or 1
            const int gi   = ch * CHUNK + il;
            float4 Brow[16];
            const float4* bsrc = (const float4*)(B + (size_t)gi * MM);
#pragma unroll
            for (int k = 0; k < 16; ++k) Brow[k] = bsrc[k];
            for (int dt = dt0g; dt < BLK; dt += 2) {
                const float4* urow = (const float4*)(&u_lds[dt][0]);
                float acc = 0.f;
#pragma unroll
                for (int k = 0; k < 16; ++k) {
                    float4 uv = urow[k];
                    acc += Brow[k].x * uv.x + Brow[k].y * uv.y +
                           Brow[k].z * uv.z + Brow[k].w * uv.w;
                }
                gbuf[dt][il] = acc;
            }
        }
        __syncthreads();

        // ---- diagonal walk (uniform dt loop -> conflict-free LDS) ----
        const int nxt = cur ^ 1;
        if (tid < BLK - 1 + CHUNK) {             // 191 diagonals
            const int cl  = tid - (BLK - 1);     // local diag: -63..127
            const int dlo = cl < 0 ? -cl : 0;
            const int dhi = min(BLK - 1, CHUNK - 1 - cl);
            float carry;
            if (cl < 0) {
                carry = colBuf[cur][dlo - 1];    // continue from prev chunk
            } else {
                const int gi = ch * CHUNK + cl;  // diag starts at row t0
                if (FULL)
                    carry = (gi >= 1)
                        ? Rbuf[((size_t)b * NBLK + blk) * NS + gi - 1] : 0.f;
                else
                    carry = 0.f;                 // S counts in-block only
            }
            for (int dt = 0; dt < BLK; ++dt) {
                if (dt >= dlo && dt <= dhi) {
                    const int il = cl + dt;
                    carry += gbuf[dt][il];
                    if (FULL) gbuf[dt][il] = carry;   // in-place G
                    if (il == CHUNK - 1) {
                        if (ch == NCHUNK - 1) {
                            if (FULL) fbuf[(size_t)b * TT + t0 + dt] = carry;
                        } else if (dt < BLK - 1) {
                            colBuf[nxt][dt] = carry;  // hand off to next chunk
                        }
                    }
                    if (!FULL && dt == BLK - 1) {
                        Sbuf[((size_t)b * NBLK + blk) * NS + ch * CHUNK + il] =
                            carry;
                    }
                }
            }
        }
        __syncthreads();

        // ---- accumulate y_part += C[:,chunk] * G[chunk] ----
        if (FULL) {
            const int p   = tid & 63;
            const int dtg = tid >> 6;
            const float* Crow = Cm + (size_t)p * NS + ch * CHUNK;
            for (int i4 = 0; i4 < CHUNK; i4 += 4) {
                const float4 cv = *(const float4*)(Crow + i4);
#pragma unroll
                for (int k = 0; k < 16; ++k) {
                    const float4 gv = *(const float4*)(&gbuf[dtg * 16 + k][i4]);
                    yacc[k] += cv.x * gv.x + cv.y * gv.y + cv.z * gv.z +
                               cv.w * gv.w;
                }
            }
        }
        __syncthreads();
        cur ^= 1;
    }

    // ---- y_part = C*G + D*u ----
    if (FULL) {
        const int p   = tid & 63;
        const int dtg = tid >> 6;
        const float4* Dp = (const float4*)(Dm + (size_t)p * MM);
#pragma unroll
        for (int k = 0; k < 16; ++k) {
            const int dt = dtg * 16 + k;
            const float4* urow = (const float4*)(&u_lds[dt][0]);
            float acc = yacc[k];
#pragma unroll
            for (int m4 = 0; m4 < 16; ++m4) {
                float4 uv = urow[m4];
                float4 dv = Dp[m4];
                acc += dv.x * uv.x + dv.y * uv.y + dv.z * uv.z + dv.w * uv.w;
            }
            y[((size_t)b * TT + t0 + dt) * PP + p] = acc;
        }
    }
}

// ---------------------------------------------------------------------------
// Block-carry scan: R_{k+1}[i] = S_k[i] + R_k[i-BLK],  R_0 = 0.
// R_k[i] = G_{t_k - 1}[i]. One WG per batch, 32 sequential tiny steps.
// ---------------------------------------------------------------------------
__global__ void __launch_bounds__(256) scan_kernel(const float* __restrict__ Sbuf,
                                                   float* __restrict__ Rbuf) {
    __shared__ float Rc[NS];
    const int b = blockIdx.x, tid = threadIdx.x;
    for (int i = tid; i < NS; i += 256) Rc[i] = 0.f;
    __syncthreads();
    for (int k = 0; k < NBLK; ++k) {
        float v[2];
#pragma unroll
        for (int r = 0; r < 2; ++r) {
            const int i = tid + 256 * r;
            Rbuf[((size_t)b * NBLK + k) * NS + i] = Rc[i];
            const float prev = (i >= BLK) ? Rc[i - BLK] : 0.f;
            v[r] = Sbuf[((size_t)b * NBLK + k) * NS + i] + prev;
        }
        __syncthreads();
#pragma unroll
        for (int r = 0; r < 2; ++r) Rc[tid + 256 * r] = v[r];
        __syncthreads();
    }
}

// ---------------------------------------------------------------------------
// Scalar IIR: s_t = f_t - sum_{j=1..NS} a[j-1] s_{t-j}. One WG per batch.
// Blocked: cross-block taps in parallel (256 thr), in-block solve via the
// truncated impulse response g (inverse of the unit-lower-tri Toeplitz).
// ---------------------------------------------------------------------------
__global__ void __launch_bounds__(256) iir_kernel(const float* __restrict__ a,
                                                  const float* __restrict__ fbuf,
                                                  float* __restrict__ sbuf) {
    __shared__ float a_l[NS];
    __shared__ float s_l[TT];
    __shared__ float g_l[BLK];
    __shared__ float rhs[BLK];
    __shared__ float part[BLK][4];
    const int b = blockIdx.x, tid = threadIdx.x;
    for (int i = tid; i < NS; i += 256) a_l[i] = a[i];
    __syncthreads();
    // g_0 = 1; g_t = -sum_{j=1..t} a[j-1] g_{t-j}   (wave 0, lane-parallel)
    if (tid < 64) {
        if (tid == 0) g_l[0] = 1.f;
        for (int t = 1; t < BLK; ++t) {
            float pr = 0.f;
            if (tid < t) pr = a_l[tid] * g_l[t - 1 - tid];
#pragma unroll
            for (int off = 32; off > 0; off >>= 1) pr += __shfl_xor(pr, off);
            if (tid == 0) g_l[t] = -pr;
        }
    }
    __syncthreads();
    const int k = tid & 63, grp = tid >> 6;
    for (int blkI = 0; blkI < NBLK; ++blkI) {
        const int t0 = blkI * BLK;
        // cross-block: C_k = sum_{d=1..min(NS-k,t0)} a[k+d-1] * s[t0-d]
        const int dmax = min(NS - k, t0);
        const int dLo = 1 + grp * 128;
        const int dHi = min(dmax, (grp + 1) * 128);
        float acc = 0.f;
        for (int d = dLo; d <= dHi; ++d) acc += a_l[k + d - 1] * s_l[t0 - d];
        part[k][grp] = acc;
        __syncthreads();
        if (tid < 64) {
            const float c = part[tid][0] + part[tid][1] + part[tid][2] +
                            part[tid][3];
            rhs[tid] = fbuf[(size_t)b * TT + t0 + tid] - c;
        }
        __syncthreads();
        // in-block: s_{t0+k} = sum_{j<=k} g_j * rhs_{k-j}
        if (tid < 64) {
            float sv = 0.f;
            for (int j = 0; j <= tid; ++j) sv += g_l[j] * rhs[tid - j];
            s_l[t0 + tid] = sv;
            sbuf[(size_t)b * TT + t0 + tid] = sv;
        }
        __syncthreads();
    }
}

// ---------------------------------------------------------------------------
// y[b,t,p] -= sum_{j=0..NS-1} q[j,p] * s[b, t-1-j]
// ---------------------------------------------------------------------------
__global__ void __launch_bounds__(256) corr_kernel(const float* __restrict__ sbuf,
                                                   const float* __restrict__ q,
                                                   float* __restrict__ y) {
    __shared__ float s_l[NS + BLK];
    const int blk = blockIdx.x, b = blockIdx.y, tid = threadIdx.x;
    const int t0 = blk * BLK;
    for (int idx = tid; idx < NS + BLK; idx += 256) {
        const int t = t0 - NS + idx;
        s_l[idx] = (t >= 0) ? sbuf[(size_t)b * TT + t] : 0.f;
    }
    __syncthreads();
    const int p   = tid & 63;
    const int dtg = tid >> 6;
    float racc[16];
#pragma unroll
    for (int k = 0; k < 16; ++k) racc[k] = 0.f;
    for (int j = 0; j < NS; ++j) {
        const float qv = q[(size_t)j * PP + p];  // coalesced over lanes
#pragma unroll
        for (int k = 0; k < 16; ++k) {
            racc[k] += qv * s_l[dtg * 16 + k + NS - 1 - j];  // LDS broadcast
        }
    }
#pragma unroll
    for (int k = 0; k < 16; ++k) {
        const size_t off = ((size_t)b * TT + t0 + dtg * 16 + k) * PP + p;
        y[off] -= racc[k];
    }
}

// ---------------------------------------------------------------------------
extern "C" void kernel_launch(void* const* d_in, const int* in_sizes, int n_in,
                              void* d_out, int out_size, void* d_ws,
                              size_t ws_size, hipStream_t stream) {
    const float* u  = (const float*)d_in[0];
    const float* a  = (const float*)d_in[1];
    const float* B  = (const float*)d_in[2];
    const float* Cm = (const float*)d_in[3];
    const float* Dm = (const float*)d_in[4];
    float* y = (float*)d_out;

    float* ws   = (float*)d_ws;
    float* q    = ws;                                   // 512*64
    float* Sbuf = q + (size_t)NS * PP;                  // 32*32*512
    float* Rbuf = Sbuf + (size_t)NBATCH * NBLK * NS;    // 32*32*512
    float* fbuf = Rbuf + (size_t)NBATCH * NBLK * NS;    // 32*2048
    float* sbuf = fbuf + (size_t)NBATCH * TT;           // 32*2048
    // total ~4.85 MB of workspace

    kq_kernel<<<dim3(NS), dim3(PP), 0, stream>>>(Cm, a, q);
    tile_kernel<0><<<dim3(NBLK, NBATCH), dim3(256), 0, stream>>>(
        u, B, nullptr, nullptr, nullptr, Sbuf, nullptr, nullptr);
    scan_kernel<<<dim3(NBATCH), dim3(256), 0, stream>>>(Sbuf, Rbuf);
    tile_kernel<1><<<dim3(NBLK, NBATCH), dim3(256), 0, stream>>>(
        u, B, Cm, Dm, Rbuf, nullptr, fbuf, y);
    iir_kernel<<<dim3(NBATCH), dim3(256), 0, stream>>>(a, fbuf, sbuf);
    corr_kernel<<<dim3(NBLK, NBATCH), dim3(256), 0, stream>>>(sbuf, q, y);
}

// Round 2
// 467.688 us; speedup vs baseline: 3.1109x; 3.1109x over previous
//
#include <hip/hip_runtime.h>

// Problem constants
#define SEQ  2048
#define NB   32
#define NS   512
#define MI   64   // M_IN
#define PO   64   // P_OUT
#define TB   64   // t-block
#define NTB  32   // SEQ/TB
#define CH   64   // i-chunk
#define NCH  8    // NS/CH
#define LDU  72   // u_b / Sw stride (ushort)
#define LDB  72   // Bm stride (ushort)
#define LDC  72   // Cm/Qm stride (ushort)
#define LDBU 68   // bu stride (float)

typedef __attribute__((ext_vector_type(8))) __bf16 bf16x8;
typedef __attribute__((ext_vector_type(4))) float  floatx4;

__device__ inline unsigned short f2bf(float f) {
    unsigned u = __builtin_bit_cast(unsigned, f);
    u += 0x7fff + ((u >> 16) & 1);           // RNE
    return (unsigned short)(u >> 16);
}

__device__ inline bf16x8 cvt8(floatx4 lo, floatx4 hi) {
    bf16x8 r;
    r[0] = (__bf16)lo[0]; r[1] = (__bf16)lo[1]; r[2] = (__bf16)lo[2]; r[3] = (__bf16)lo[3];
    r[4] = (__bf16)hi[0]; r[5] = (__bf16)hi[1]; r[6] = (__bf16)hi[2]; r[7] = (__bf16)hi[3];
    return r;
}

// ---------------------------------------------------------------------------
// One-time fp32 -> bf16 conversion of B (512x64), C (64x512), D (64x64)
// ---------------------------------------------------------------------------
__global__ void __launch_bounds__(256) prep_kernel(
    const float* __restrict__ B, const float* __restrict__ C,
    const float* __restrict__ D, unsigned short* __restrict__ Bws,
    unsigned short* __restrict__ Cws, unsigned short* __restrict__ Dws) {
    const int idx = blockIdx.x * 256 + threadIdx.x;
    const int nB = NS * MI, nC = PO * NS, nD = PO * MI;
    if (idx < nB) Bws[idx] = f2bf(B[idx]);
    else if (idx < nB + nC) Cws[idx - nB] = f2bf(C[idx - nB]);
    else if (idx < nB + nC + nD) Dws[idx - nB - nC] = f2bf(D[idx - nB - nC]);
}

// ---------------------------------------------------------------------------
// qT[p][j] = sum_{i=j}^{NS-1} C[p,i] * a[NS-1-i+j]   (bf16, transposed layout)
// ---------------------------------------------------------------------------
__global__ void __launch_bounds__(64) kq_kernel(const float* __restrict__ Cmat,
                                                const float* __restrict__ a,
                                                unsigned short* __restrict__ qT) {
    const int j = blockIdx.x, p = threadIdx.x;
    float acc = 0.f;
    for (int i = j; i < NS; ++i) acc += Cmat[p * NS + i] * a[NS - 1 - i + j];
    qT[(size_t)p * NS + j] = f2bf(acc);
}

// ---------------------------------------------------------------------------
// Tile kernel (MFMA). One WG per (tau-block, batch). i-chunks of 64 in LDS.
// Phase A: bu[t][i] = B[i,:].u[t,:] via mfma 16x16x32 bf16.
// Walk: fp32 diagonal cumsum in place (FULL) or diagonal block-sums S (!FULL).
// Phase B (FULL): y += C*G (+ D*u at end), G converted fp32->bf16 on the fly.
// ---------------------------------------------------------------------------
template <int FULL>
__global__ void __launch_bounds__(256, 3) tile_kernel(
    const float* __restrict__ u, const unsigned short* __restrict__ Bws,
    const unsigned short* __restrict__ Cws, const unsigned short* __restrict__ Dws,
    const float* __restrict__ Rbuf, float* __restrict__ Sbuf,
    float* __restrict__ fbuf, float* __restrict__ y) {
    __shared__ unsigned short u_b[TB * LDU];   // [t][m] bf16
    __shared__ unsigned short Bm[CH * LDB];    // [i_local][m] bf16
    __shared__ unsigned short Cm[PO * LDC];    // [p][i_local] bf16 (and D at end)
    __shared__ float bu[TB * LDBU];            // [t][i_local] fp32 (Bu, then G)
    __shared__ float colBuf[2][TB];

    const int blk = blockIdx.x, b = blockIdx.y;
    const int t0 = blk * TB;
    const int tid = threadIdx.x;
    const int lane = tid & 63, w = tid >> 6;

    // ---- stage u tile fp32 -> bf16 [t][m] ----
    {
        const int t = tid >> 2, m0 = (tid & 3) * 16;
        const float4* src = (const float4*)(u + ((size_t)b * SEQ + t0 + t) * MI + m0);
        unsigned short tmp[16];
#pragma unroll
        for (int q2 = 0; q2 < 4; ++q2) {
            float4 f = src[q2];
            tmp[q2 * 4 + 0] = f2bf(f.x); tmp[q2 * 4 + 1] = f2bf(f.y);
            tmp[q2 * 4 + 2] = f2bf(f.z); tmp[q2 * 4 + 3] = f2bf(f.w);
        }
        *(uint4*)&u_b[t * LDU + m0]     = *(uint4*)&tmp[0];
        *(uint4*)&u_b[t * LDU + m0 + 8] = *(uint4*)&tmp[8];
    }
    if (tid < TB) colBuf[0][tid] = 0.f;

    floatx4 accY[4];
    if (FULL) {
#pragma unroll
        for (int nt = 0; nt < 4; ++nt) accY[nt] = (floatx4){0.f, 0.f, 0.f, 0.f};
    }
    __syncthreads();

    int cur = 0;
    for (int ch = 0; ch < NCH; ++ch) {
        // ---- stage B chunk (+C chunk if FULL) bf16 ----
        {
            const int r = tid >> 2, c0 = (tid & 3) * 16;
            const uint4* bs = (const uint4*)(Bws + (size_t)(ch * CH + r) * MI + c0);
            uint4 v0 = bs[0], v1 = bs[1];
            *(uint4*)&Bm[r * LDB + c0]     = v0;
            *(uint4*)&Bm[r * LDB + c0 + 8] = v1;
            if (FULL) {
                const uint4* cs = (const uint4*)(Cws + (size_t)r * NS + ch * CH + c0);
                uint4 w0 = cs[0], w1 = cs[1];
                *(uint4*)&Cm[r * LDC + c0]     = w0;
                *(uint4*)&Cm[r * LDC + c0 + 8] = w1;
            }
        }
        __syncthreads();

        // ---- phase A: MFMA Bu chunk; wave w -> i-strip w ----
        {
            const bf16x8 a0 = *(const bf16x8*)&Bm[(w * 16 + (lane & 15)) * LDB + ((lane >> 4) * 8)];
            const bf16x8 a1 = *(const bf16x8*)&Bm[(w * 16 + (lane & 15)) * LDB + 32 + ((lane >> 4) * 8)];
#pragma unroll
            for (int nt = 0; nt < 4; ++nt) {
                const int t = nt * 16 + (lane & 15);
                bf16x8 b0 = *(const bf16x8*)&u_b[t * LDU + ((lane >> 4) * 8)];
                bf16x8 b1 = *(const bf16x8*)&u_b[t * LDU + 32 + ((lane >> 4) * 8)];
                floatx4 d = {0.f, 0.f, 0.f, 0.f};
                d = __builtin_amdgcn_mfma_f32_16x16x32_bf16(a0, b0, d, 0, 0, 0);
                d = __builtin_amdgcn_mfma_f32_16x16x32_bf16(a1, b1, d, 0, 0, 0);
                *(floatx4*)&bu[t * LDBU + w * 16 + ((lane >> 4) * 4)] = d;
            }
        }
        __syncthreads();

        // ---- diagonal walk (2 waves; fp32) ----
        const int nxt = cur ^ 1;
        if (tid < 127) {
            const int cl  = tid - 63;                    // local diag i - t
            const int tlo = cl < 0 ? -cl : 0;
            const int thi = cl > 0 ? 63 - cl : 63;
            float carry;
            if (cl < 0) carry = colBuf[cur][tlo - 1];
            else if (FULL) {
                const int gi = ch * CH + cl;
                carry = (gi >= 1) ? Rbuf[((size_t)b * NTB + blk) * NS + gi - 1] : 0.f;
            } else carry = 0.f;
            for (int t = tlo; t <= thi; ++t) {
                const int il = cl + t;
                carry += bu[t * LDBU + il];
                if (FULL) bu[t * LDBU + il] = carry;     // in-place G
            }
            if (cl > 0) {
                if (ch == NCH - 1) { if (FULL) fbuf[(size_t)b * SEQ + t0 + 63 - cl] = carry; }
                else colBuf[nxt][63 - cl] = carry;
            } else {
                if (FULL) { if (ch == NCH - 1 && cl == 0) fbuf[(size_t)b * SEQ + t0 + 63] = carry; }
                else Sbuf[((size_t)b * NTB + blk) * NS + ch * CH + cl + 63] = carry;
            }
        }
        __syncthreads();

        // ---- phase B (FULL): accY += C[:,chunk] * G[chunk]; wave w -> p-strip ----
        if (FULL) {
            const bf16x8 ca0 = *(const bf16x8*)&Cm[(w * 16 + (lane & 15)) * LDC + ((lane >> 4) * 8)];
            const bf16x8 ca1 = *(const bf16x8*)&Cm[(w * 16 + (lane & 15)) * LDC + 32 + ((lane >> 4) * 8)];
#pragma unroll
            for (int nt = 0; nt < 4; ++nt) {
                const int t  = nt * 16 + (lane & 15);
                const int k0 = (lane >> 4) * 8;
                floatx4 g0 = *(const floatx4*)&bu[t * LDBU + k0];
                floatx4 g1 = *(const floatx4*)&bu[t * LDBU + k0 + 4];
                floatx4 h0 = *(const floatx4*)&bu[t * LDBU + 32 + k0];
                floatx4 h1 = *(const floatx4*)&bu[t * LDBU + 32 + k0 + 4];
                accY[nt] = __builtin_amdgcn_mfma_f32_16x16x32_bf16(ca0, cvt8(g0, g1), accY[nt], 0, 0, 0);
                accY[nt] = __builtin_amdgcn_mfma_f32_16x16x32_bf16(ca1, cvt8(h0, h1), accY[nt], 0, 0, 0);
            }
        }
        __syncthreads();
        cur = nxt;
    }

    // ---- epilogue (FULL): += D*u, store y ----
    if (FULL) {
        {
            const int r = tid >> 2, c0 = (tid & 3) * 16;
            const uint4* ds = (const uint4*)(Dws + (size_t)r * MI + c0);
            uint4 v0 = ds[0], v1 = ds[1];
            *(uint4*)&Cm[r * LDC + c0]     = v0;
            *(uint4*)&Cm[r * LDC + c0 + 8] = v1;
        }
        __syncthreads();
        const bf16x8 da0 = *(const bf16x8*)&Cm[(w * 16 + (lane & 15)) * LDC + ((lane >> 4) * 8)];
        const bf16x8 da1 = *(const bf16x8*)&Cm[(w * 16 + (lane & 15)) * LDC + 32 + ((lane >> 4) * 8)];
#pragma unroll
        for (int nt = 0; nt < 4; ++nt) {
            const int t = nt * 16 + (lane & 15);
            bf16x8 b0 = *(const bf16x8*)&u_b[t * LDU + ((lane >> 4) * 8)];
            bf16x8 b1 = *(const bf16x8*)&u_b[t * LDU + 32 + ((lane >> 4) * 8)];
            accY[nt] = __builtin_amdgcn_mfma_f32_16x16x32_bf16(da0, b0, accY[nt], 0, 0, 0);
            accY[nt] = __builtin_amdgcn_mfma_f32_16x16x32_bf16(da1, b1, accY[nt], 0, 0, 0);
            const int p0 = w * 16 + ((lane >> 4) * 4);
            *(floatx4*)(y + ((size_t)b * SEQ + t0 + t) * PO + p0) = accY[nt];
        }
    }
}

// ---------------------------------------------------------------------------
// Block-carry scan, fully in LDS: R_{k+1}[i] = S_k[i] + R_k[i-TB], R_0 = 0.
// ---------------------------------------------------------------------------
__global__ void __launch_bounds__(256) scan_kernel(const float* __restrict__ Sbuf,
                                                   float* __restrict__ Rbuf) {
    __shared__ float S_l[NTB * NS];    // 64 KB
    __shared__ float Rc[2][NS];
    const int b = blockIdx.x, tid = threadIdx.x;
    const float4* src = (const float4*)(Sbuf + (size_t)b * NTB * NS);
    float4* dst = (float4*)S_l;
    for (int k = tid; k < NTB * NS / 4; k += 256) dst[k] = src[k];
    if (tid < 128) ((float4*)Rc[0])[tid] = make_float4(0.f, 0.f, 0.f, 0.f);
    __syncthreads();
    int cur = 0;
    for (int k = 0; k < NTB; ++k) {
        if (tid < 128) {
            const int i0 = tid * 4;
            float4 r = ((const float4*)Rc[cur])[tid];
            *(float4*)(Rbuf + ((size_t)b * NTB + k) * NS + i0) = r;
            float4 s = *(const float4*)&S_l[k * NS + i0];
            float4 rp = (i0 >= TB) ? *(const float4*)&Rc[cur][i0 - TB]
                                   : make_float4(0.f, 0.f, 0.f, 0.f);
            float4 nv = make_float4(s.x + rp.x, s.y + rp.y, s.z + rp.z, s.w + rp.w);
            *(float4*)&Rc[cur ^ 1][i0] = nv;
        }
        __syncthreads();
        cur ^= 1;
    }
}

// ---------------------------------------------------------------------------
// Scalar IIR: s_t = f_t - sum_{j=1..NS} a[j-1] s_{t-j}. One WG per batch.
// (unchanged from verified round-1 version)
// ---------------------------------------------------------------------------
__global__ void __launch_bounds__(256) iir_kernel(const float* __restrict__ a,
                                                  const float* __restrict__ fbuf,
                                                  float* __restrict__ sbuf) {
    __shared__ float a_l[NS];
    __shared__ float s_l[SEQ];
    __shared__ float g_l[TB];
    __shared__ float rhs[TB];
    __shared__ float part[TB][4];
    const int b = blockIdx.x, tid = threadIdx.x;
    for (int i = tid; i < NS; i += 256) a_l[i] = a[i];
    __syncthreads();
    if (tid < 64) {
        if (tid == 0) g_l[0] = 1.f;
        for (int t = 1; t < TB; ++t) {
            float pr = 0.f;
            if (tid < t) pr = a_l[tid] * g_l[t - 1 - tid];
#pragma unroll
            for (int off = 32; off > 0; off >>= 1) pr += __shfl_xor(pr, off);
            if (tid == 0) g_l[t] = -pr;
        }
    }
    __syncthreads();
    const int k = tid & 63, grp = tid >> 6;
    for (int blkI = 0; blkI < NTB; ++blkI) {
        const int t0 = blkI * TB;
        const int dmax = min(NS - k, t0);
        const int dLo = 1 + grp * 128;
        const int dHi = min(dmax, (grp + 1) * 128);
        float acc = 0.f;
        for (int d = dLo; d <= dHi; ++d) acc += a_l[k + d - 1] * s_l[t0 - d];
        part[k][grp] = acc;
        __syncthreads();
        if (tid < 64) {
            const float c = part[tid][0] + part[tid][1] + part[tid][2] + part[tid][3];
            rhs[tid] = fbuf[(size_t)b * SEQ + t0 + tid] - c;
        }
        __syncthreads();
        if (tid < 64) {
            float sv = 0.f;
            for (int j = 0; j <= tid; ++j) sv += g_l[j] * rhs[tid - j];
            s_l[t0 + tid] = sv;
            sbuf[(size_t)b * SEQ + t0 + tid] = sv;
        }
        __syncthreads();
    }
}

// ---------------------------------------------------------------------------
// corr (MFMA): y[b,t,p] -= sum_j qT[p][j] * s[b, t-1-j]
// ---------------------------------------------------------------------------
__global__ void __launch_bounds__(256) corr_kernel(
    const float* __restrict__ sbuf, const unsigned short* __restrict__ qT,
    float* __restrict__ y) {
    __shared__ float s_l[NS + TB];             // window [t0-512 .. t0+63]
    __shared__ unsigned short Qm[PO * LDC];    // [p][j_local]
    __shared__ unsigned short Sw[TB * LDU];    // [t][j_local]
    const int blk = blockIdx.x, b = blockIdx.y, tid = threadIdx.x;
    const int t0 = blk * TB;
    const int lane = tid & 63, w = tid >> 6;
    for (int idx = tid; idx < NS + TB; idx += 256) {
        const int t = t0 - NS + idx;
        s_l[idx] = (t >= 0) ? sbuf[(size_t)b * SEQ + t] : 0.f;
    }
    floatx4 acc[4];
#pragma unroll
    for (int nt = 0; nt < 4; ++nt) acc[nt] = (floatx4){0.f, 0.f, 0.f, 0.f};
    __syncthreads();

    for (int ch = 0; ch < NCH; ++ch) {
        const int r = tid >> 2, c0 = (tid & 3) * 16;
        {
            const uint4* qs = (const uint4*)(qT + (size_t)r * NS + ch * CH + c0);
            uint4 v0 = qs[0], v1 = qs[1];
            *(uint4*)&Qm[r * LDC + c0]     = v0;
            *(uint4*)&Qm[r * LDC + c0 + 8] = v1;
        }
        {
            // Sw[t][j] = bf16(s[t0+t-1-(ch*64+j)]) = bf16(s_l[511 + t - ch*64 - j])
            unsigned short tmp[16];
            const int base = 511 + r - ch * CH - c0;
#pragma unroll
            for (int jj = 0; jj < 16; ++jj) tmp[jj] = f2bf(s_l[base - jj]);
            *(uint4*)&Sw[r * LDU + c0]     = *(uint4*)&tmp[0];
            *(uint4*)&Sw[r * LDU + c0 + 8] = *(uint4*)&tmp[8];
        }
        __syncthreads();
        const bf16x8 qa0 = *(const bf16x8*)&Qm[(w * 16 + (lane & 15)) * LDC + ((lane >> 4) * 8)];
        const bf16x8 qa1 = *(const bf16x8*)&Qm[(w * 16 + (lane & 15)) * LDC + 32 + ((lane >> 4) * 8)];
#pragma unroll
        for (int nt = 0; nt < 4; ++nt) {
            const int t = nt * 16 + (lane & 15);
            bf16x8 s0 = *(const bf16x8*)&Sw[t * LDU + ((lane >> 4) * 8)];
            bf16x8 s1 = *(const bf16x8*)&Sw[t * LDU + 32 + ((lane >> 4) * 8)];
            acc[nt] = __builtin_amdgcn_mfma_f32_16x16x32_bf16(qa0, s0, acc[nt], 0, 0, 0);
            acc[nt] = __builtin_amdgcn_mfma_f32_16x16x32_bf16(qa1, s1, acc[nt], 0, 0, 0);
        }
        __syncthreads();
    }
#pragma unroll
    for (int nt = 0; nt < 4; ++nt) {
        const int t = nt * 16 + (lane & 15);
        const int p0 = w * 16 + ((lane >> 4) * 4);
        float* yp = y + ((size_t)b * SEQ + t0 + t) * PO + p0;
        floatx4 old = *(const floatx4*)yp;
        *(floatx4*)yp = old - acc[nt];
    }
}

// ---------------------------------------------------------------------------
extern "C" void kernel_launch(void* const* d_in, const int* in_sizes, int n_in,
                              void* d_out, int out_size, void* d_ws,
                              size_t ws_size, hipStream_t stream) {
    const float* u  = (const float*)d_in[0];
    const float* a  = (const float*)d_in[1];
    const float* B  = (const float*)d_in[2];
    const float* Cm = (const float*)d_in[3];
    const float* Dm = (const float*)d_in[4];
    float* y = (float*)d_out;

    char* ws = (char*)d_ws;
    unsigned short* Bws = (unsigned short*)ws;                  ws += NS * MI * 2;
    unsigned short* Cws = (unsigned short*)ws;                  ws += PO * NS * 2;
    unsigned short* Dws = (unsigned short*)ws;                  ws += PO * MI * 2;
    unsigned short* qTw = (unsigned short*)ws;                  ws += PO * NS * 2;
    float* Sbuf = (float*)ws;                                   ws += (size_t)NB * NTB * NS * 4;
    float* Rbuf = (float*)ws;                                   ws += (size_t)NB * NTB * NS * 4;
    float* fbuf = (float*)ws;                                   ws += (size_t)NB * SEQ * 4;
    float* sbuf = (float*)ws;                                   // ~4.9 MB total

    prep_kernel<<<dim3(272), dim3(256), 0, stream>>>(B, Cm, Dm, Bws, Cws, Dws);
    kq_kernel<<<dim3(NS), dim3(PO), 0, stream>>>(Cm, a, qTw);
    tile_kernel<0><<<dim3(NTB, NB), dim3(256), 0, stream>>>(
        u, Bws, Cws, Dws, nullptr, Sbuf, nullptr, nullptr);
    scan_kernel<<<dim3(NB), dim3(256), 0, stream>>>(Sbuf, Rbuf);
    tile_kernel<1><<<dim3(NTB, NB), dim3(256), 0, stream>>>(
        u, Bws, Cws, Dws, Rbuf, nullptr, fbuf, y);
    iir_kernel<<<dim3(NB), dim3(256), 0, stream>>>(a, fbuf, sbuf);
    corr_kernel<<<dim3(NTB, NB), dim3(256), 0, stream>>>(sbuf, qTw, y);
}

// Round 3
// 354.359 us; speedup vs baseline: 4.1058x; 1.3198x over previous
//
#include <hip/hip_runtime.h>

// Problem constants
#define SEQ  2048
#define NB   32
#define NS   512
#define MI   64   // M_IN
#define PO   64   // P_OUT
#define TB   64   // t-block
#define NTB  32   // SEQ/TB
#define CH   64   // i-chunk
#define NCH  8    // NS/CH
#define LDU  72   // u_b / Sw stride (ushort)
#define LDB  72   // Bm stride (ushort)
#define LDC  72   // Cm/Qm stride (ushort)
#define LDBU 68   // bu stride (float)
#define TB2  128  // h-impulse block

typedef __attribute__((ext_vector_type(8))) __bf16 bf16x8;
typedef __attribute__((ext_vector_type(4))) float  floatx4;

__device__ inline unsigned short f2bf(float f) {
    unsigned u = __builtin_bit_cast(unsigned, f);
    u += 0x7fff + ((u >> 16) & 1);           // RNE
    return (unsigned short)(u >> 16);
}

__device__ inline bf16x8 cvt8(floatx4 lo, floatx4 hi) {
    bf16x8 r;
    r[0] = (__bf16)lo[0]; r[1] = (__bf16)lo[1]; r[2] = (__bf16)lo[2]; r[3] = (__bf16)lo[3];
    r[4] = (__bf16)hi[0]; r[5] = (__bf16)hi[1]; r[6] = (__bf16)hi[2]; r[7] = (__bf16)hi[3];
    return r;
}

// ---------------------------------------------------------------------------
// One-time fp32 -> bf16 conversion of B (512x64), C (64x512), D (64x64)
// ---------------------------------------------------------------------------
__global__ void __launch_bounds__(256) prep_kernel(
    const float* __restrict__ B, const float* __restrict__ C,
    const float* __restrict__ D, unsigned short* __restrict__ Bws,
    unsigned short* __restrict__ Cws, unsigned short* __restrict__ Dws) {
    const int idx = blockIdx.x * 256 + threadIdx.x;
    const int nB = NS * MI, nC = PO * NS, nD = PO * MI;
    if (idx < nB) Bws[idx] = f2bf(B[idx]);
    else if (idx < nB + nC) Cws[idx - nB] = f2bf(C[idx - nB]);
    else if (idx < nB + nC + nD) Dws[idx - nB - nC] = f2bf(D[idx - nB - nC]);
}

// ---------------------------------------------------------------------------
// qT[p][j] = sum_{i=j}^{NS-1} C[p,i] * a[NS-1-i+j]   (bf16, transposed layout)
// ---------------------------------------------------------------------------
__global__ void __launch_bounds__(64) kq_kernel(const float* __restrict__ Cmat,
                                                const float* __restrict__ a,
                                                unsigned short* __restrict__ qT) {
    const int j = blockIdx.x, p = threadIdx.x;
    float acc = 0.f;
    for (int i = j; i < NS; ++i) acc += Cmat[p * NS + i] * a[NS - 1 - i + j];
    qT[(size_t)p * NS + j] = f2bf(acc);
}

// ---------------------------------------------------------------------------
// Impulse response of the scalar IIR:  h_0 = 1,
//   h_t = -sum_{j=1..min(t,NS)} a[j-1] h_{t-j}
// Single WG (this is the only sequential part of the whole problem).
// Bootstrap h[0:128] serially (wave 0), then 15 blocked steps of 128:
//   rhs[k] = -sum_{d} a[k+d-1] h[t0-d]   (cross-block, a register-cached)
//   h[t0+k] = sum_{j<=k} h[j] rhs[k-j]   (in-block; h[0:128] inverts the block)
// ---------------------------------------------------------------------------
__global__ void __launch_bounds__(1024) himp_kernel(const float* __restrict__ a,
                                                    float* __restrict__ hbuf) {
    __shared__ float a_l[640];          // zero-padded taps
    __shared__ float h_l[SEQ];
    __shared__ float part[16 * TB2];    // [grp][k]
    __shared__ float rhs_l[TB2];
    const int tid = threadIdx.x;
    const int kk = tid & 63, grp = tid >> 6;   // 16 groups of 64

    if (tid < NS) a_l[tid] = a[tid];
    if (tid >= NS && tid < 640) a_l[tid] = 0.f;
    __syncthreads();

    // register-cache taps: this thread handles k in {kk, kk+64},
    // d in [grp*32+1, grp*32+32]  -> tap indices k+grp*32 .. +31
    float a0r[32], a1r[32];
#pragma unroll
    for (int i = 0; i < 32; ++i) a0r[i] = a_l[kk + grp * 32 + i];
#pragma unroll
    for (int i = 0; i < 32; ++i) a1r[i] = a_l[kk + 64 + grp * 32 + i];

    // bootstrap h[0:128] (wave 0; same-wave LDS ordering — verified idiom)
    if (tid < 64) {
        if (tid == 0) h_l[0] = 1.f;
        for (int t = 1; t < TB2; ++t) {
            float pr = 0.f;
            const int j1 = tid + 1, j2 = tid + 65;
            if (j1 <= t) pr += a_l[j1 - 1] * h_l[t - j1];
            if (j2 <= t) pr += a_l[j2 - 1] * h_l[t - j2];
#pragma unroll
            for (int off = 32; off; off >>= 1) pr += __shfl_xor(pr, off);
            if (tid == 0) h_l[t] = -pr;
        }
    }
    __syncthreads();

    for (int t0 = TB2; t0 < SEQ; t0 += TB2) {
        float acc0 = 0.f, acc1 = 0.f;
        if (grp * 32 < t0) {   // d-range valid (t0 multiple of 128)
#pragma unroll
            for (int m = 0; m < 8; ++m) {
                const float4 hv = *(const float4*)&h_l[t0 - grp * 32 - 4 - 4 * m];
                // d = grp*32 + 4m + 1 + ii ; h[t0-d] = hv[3-ii]
                acc0 += a0r[4 * m + 0] * hv.w + a0r[4 * m + 1] * hv.z +
                        a0r[4 * m + 2] * hv.y + a0r[4 * m + 3] * hv.x;
                acc1 += a1r[4 * m + 0] * hv.w + a1r[4 * m + 1] * hv.z +
                        a1r[4 * m + 2] * hv.y + a1r[4 * m + 3] * hv.x;
            }
        }
        part[grp * TB2 + kk]      = acc0;
        part[grp * TB2 + kk + 64] = acc1;
        __syncthreads();
        if (tid < TB2) {
            float r = 0.f;
#pragma unroll
            for (int g = 0; g < 16; ++g) r += part[g * TB2 + tid];
            rhs_l[tid] = -r;
        }
        __syncthreads();
        if (tid < TB2) {
            float sv = 0.f;
            for (int j = 0; j <= tid; ++j) sv += h_l[j] * rhs_l[tid - j];
            h_l[t0 + tid] = sv;
        }
        __syncthreads();
    }
    for (int i = tid; i < SEQ; i += 1024) hbuf[i] = h_l[i];
}

// ---------------------------------------------------------------------------
// s[b][t] = sum_{j=0..t} h[j] f[b][t-j]   (exact triangular conv, fp32)
// ---------------------------------------------------------------------------
__global__ void __launch_bounds__(256) sconv_kernel(const float* __restrict__ fbuf,
                                                    const float* __restrict__ hbuf,
                                                    float* __restrict__ sbuf) {
    __shared__ float f_l[SEQ];
    __shared__ float h_lc[SEQ + 8];
    __shared__ float part[4][TB];
    const int blk = blockIdx.x, b = blockIdx.y, tid = threadIdx.x;
    const int t0 = blk * TB;
    const int len = t0 + TB;
    {
        const float4* fs = (const float4*)(fbuf + (size_t)b * SEQ);
        const float4* hs = (const float4*)hbuf;
        for (int i = tid; i < len / 4; i += 256) {
            ((float4*)f_l)[i] = fs[i];
            ((float4*)h_lc)[i] = hs[i];
        }
    }
    __syncthreads();
    const int dt = tid & 63, grp = tid >> 6;
    const int t = t0 + dt;
    float acc = 0.f;
    for (int j4 = grp * 4; j4 <= t; j4 += 16) {
        const float4 hv = *(const float4*)&h_lc[j4];
        if (j4 + 0 <= t) acc += hv.x * f_l[t - j4 - 0];
        if (j4 + 1 <= t) acc += hv.y * f_l[t - j4 - 1];
        if (j4 + 2 <= t) acc += hv.z * f_l[t - j4 - 2];
        if (j4 + 3 <= t) acc += hv.w * f_l[t - j4 - 3];
    }
    part[grp][dt] = acc;
    __syncthreads();
    if (tid < TB) {
        sbuf[(size_t)b * SEQ + t0 + tid] =
            part[0][tid] + part[1][tid] + part[2][tid] + part[3][tid];
    }
}

// ---------------------------------------------------------------------------
// Tile kernel (MFMA). One WG per (tau-block, batch). i-chunks of 64 in LDS.
// ---------------------------------------------------------------------------
template <int FULL>
__global__ void __launch_bounds__(256, 3) tile_kernel(
    const float* __restrict__ u, const unsigned short* __restrict__ Bws,
    const unsigned short* __restrict__ Cws, const unsigned short* __restrict__ Dws,
    const float* __restrict__ Rbuf, float* __restrict__ Sbuf,
    float* __restrict__ fbuf, float* __restrict__ y) {
    __shared__ unsigned short u_b[TB * LDU];   // [t][m] bf16
    __shared__ unsigned short Bm[CH * LDB];    // [i_local][m] bf16
    __shared__ unsigned short Cm[PO * LDC];    // [p][i_local] bf16 (and D at end)
    __shared__ float bu[TB * LDBU];            // [t][i_local] fp32 (Bu, then G)
    __shared__ float colBuf[2][TB];

    const int blk = blockIdx.x, b = blockIdx.y;
    const int t0 = blk * TB;
    const int tid = threadIdx.x;
    const int lane = tid & 63, w = tid >> 6;

    {
        const int t = tid >> 2, m0 = (tid & 3) * 16;
        const float4* src = (const float4*)(u + ((size_t)b * SEQ + t0 + t) * MI + m0);
        unsigned short tmp[16];
#pragma unroll
        for (int q2 = 0; q2 < 4; ++q2) {
            float4 f = src[q2];
            tmp[q2 * 4 + 0] = f2bf(f.x); tmp[q2 * 4 + 1] = f2bf(f.y);
            tmp[q2 * 4 + 2] = f2bf(f.z); tmp[q2 * 4 + 3] = f2bf(f.w);
        }
        *(uint4*)&u_b[t * LDU + m0]     = *(uint4*)&tmp[0];
        *(uint4*)&u_b[t * LDU + m0 + 8] = *(uint4*)&tmp[8];
    }
    if (tid < TB) colBuf[0][tid] = 0.f;

    floatx4 accY[4];
    if (FULL) {
#pragma unroll
        for (int nt = 0; nt < 4; ++nt) accY[nt] = (floatx4){0.f, 0.f, 0.f, 0.f};
    }
    __syncthreads();

    int cur = 0;
    for (int ch = 0; ch < NCH; ++ch) {
        {
            const int r = tid >> 2, c0 = (tid & 3) * 16;
            const uint4* bs = (const uint4*)(Bws + (size_t)(ch * CH + r) * MI + c0);
            uint4 v0 = bs[0], v1 = bs[1];
            *(uint4*)&Bm[r * LDB + c0]     = v0;
            *(uint4*)&Bm[r * LDB + c0 + 8] = v1;
            if (FULL) {
                const uint4* cs = (const uint4*)(Cws + (size_t)r * NS + ch * CH + c0);
                uint4 w0 = cs[0], w1 = cs[1];
                *(uint4*)&Cm[r * LDC + c0]     = w0;
                *(uint4*)&Cm[r * LDC + c0 + 8] = w1;
            }
        }
        __syncthreads();

        {
            const bf16x8 a0 = *(const bf16x8*)&Bm[(w * 16 + (lane & 15)) * LDB + ((lane >> 4) * 8)];
            const bf16x8 a1 = *(const bf16x8*)&Bm[(w * 16 + (lane & 15)) * LDB + 32 + ((lane >> 4) * 8)];
#pragma unroll
            for (int nt = 0; nt < 4; ++nt) {
                const int t = nt * 16 + (lane & 15);
                bf16x8 b0 = *(const bf16x8*)&u_b[t * LDU + ((lane >> 4) * 8)];
                bf16x8 b1 = *(const bf16x8*)&u_b[t * LDU + 32 + ((lane >> 4) * 8)];
                floatx4 d = {0.f, 0.f, 0.f, 0.f};
                d = __builtin_amdgcn_mfma_f32_16x16x32_bf16(a0, b0, d, 0, 0, 0);
                d = __builtin_amdgcn_mfma_f32_16x16x32_bf16(a1, b1, d, 0, 0, 0);
                *(floatx4*)&bu[t * LDBU + w * 16 + ((lane >> 4) * 4)] = d;
            }
        }
        __syncthreads();

        const int nxt = cur ^ 1;
        if (tid < 127) {
            const int cl  = tid - 63;
            const int tlo = cl < 0 ? -cl : 0;
            const int thi = cl > 0 ? 63 - cl : 63;
            float carry;
            if (cl < 0) carry = colBuf[cur][tlo - 1];
            else if (FULL) {
                const int gi = ch * CH + cl;
                carry = (gi >= 1) ? Rbuf[((size_t)b * NTB + blk) * NS + gi - 1] : 0.f;
            } else carry = 0.f;
            for (int t = tlo; t <= thi; ++t) {
                const int il = cl + t;
                carry += bu[t * LDBU + il];
                if (FULL) bu[t * LDBU + il] = carry;
            }
            if (cl > 0) {
                if (ch == NCH - 1) { if (FULL) fbuf[(size_t)b * SEQ + t0 + 63 - cl] = carry; }
                else colBuf[nxt][63 - cl] = carry;
            } else {
                if (FULL) { if (ch == NCH - 1 && cl == 0) fbuf[(size_t)b * SEQ + t0 + 63] = carry; }
                else Sbuf[((size_t)b * NTB + blk) * NS + ch * CH + cl + 63] = carry;
            }
        }
        __syncthreads();

        if (FULL) {
            const bf16x8 ca0 = *(const bf16x8*)&Cm[(w * 16 + (lane & 15)) * LDC + ((lane >> 4) * 8)];
            const bf16x8 ca1 = *(const bf16x8*)&Cm[(w * 16 + (lane & 15)) * LDC + 32 + ((lane >> 4) * 8)];
#pragma unroll
            for (int nt = 0; nt < 4; ++nt) {
                const int t  = nt * 16 + (lane & 15);
                const int k0 = (lane >> 4) * 8;
                floatx4 g0 = *(const floatx4*)&bu[t * LDBU + k0];
                floatx4 g1 = *(const floatx4*)&bu[t * LDBU + k0 + 4];
                floatx4 h0 = *(const floatx4*)&bu[t * LDBU + 32 + k0];
                floatx4 h1 = *(const floatx4*)&bu[t * LDBU + 32 + k0 + 4];
                accY[nt] = __builtin_amdgcn_mfma_f32_16x16x32_bf16(ca0, cvt8(g0, g1), accY[nt], 0, 0, 0);
                accY[nt] = __builtin_amdgcn_mfma_f32_16x16x32_bf16(ca1, cvt8(h0, h1), accY[nt], 0, 0, 0);
            }
        }
        __syncthreads();
        cur = nxt;
    }

    if (FULL) {
        {
            const int r = tid >> 2, c0 = (tid & 3) * 16;
            const uint4* ds = (const uint4*)(Dws + (size_t)r * MI + c0);
            uint4 v0 = ds[0], v1 = ds[1];
            *(uint4*)&Cm[r * LDC + c0]     = v0;
            *(uint4*)&Cm[r * LDC + c0 + 8] = v1;
        }
        __syncthreads();
        const bf16x8 da0 = *(const bf16x8*)&Cm[(w * 16 + (lane & 15)) * LDC + ((lane >> 4) * 8)];
        const bf16x8 da1 = *(const bf16x8*)&Cm[(w * 16 + (lane & 15)) * LDC + 32 + ((lane >> 4) * 8)];
#pragma unroll
        for (int nt = 0; nt < 4; ++nt) {
            const int t = nt * 16 + (lane & 15);
            bf16x8 b0 = *(const bf16x8*)&u_b[t * LDU + ((lane >> 4) * 8)];
            bf16x8 b1 = *(const bf16x8*)&u_b[t * LDU + 32 + ((lane >> 4) * 8)];
            accY[nt] = __builtin_amdgcn_mfma_f32_16x16x32_bf16(da0, b0, accY[nt], 0, 0, 0);
            accY[nt] = __builtin_amdgcn_mfma_f32_16x16x32_bf16(da1, b1, accY[nt], 0, 0, 0);
            const int p0 = w * 16 + ((lane >> 4) * 4);
            *(floatx4*)(y + ((size_t)b * SEQ + t0 + t) * PO + p0) = accY[nt];
        }
    }
}

// ---------------------------------------------------------------------------
// Block-carry scan, fully in LDS: R_{k+1}[i] = S_k[i] + R_k[i-TB], R_0 = 0.
// ---------------------------------------------------------------------------
__global__ void __launch_bounds__(256) scan_kernel(const float* __restrict__ Sbuf,
                                                   float* __restrict__ Rbuf) {
    __shared__ float S_l[NTB * NS];
    __shared__ float Rc[2][NS];
    const int b = blockIdx.x, tid = threadIdx.x;
    const float4* src = (const float4*)(Sbuf + (size_t)b * NTB * NS);
    float4* dst = (float4*)S_l;
    for (int k = tid; k < NTB * NS / 4; k += 256) dst[k] = src[k];
    if (tid < 128) ((float4*)Rc[0])[tid] = make_float4(0.f, 0.f, 0.f, 0.f);
    __syncthreads();
    int cur = 0;
    for (int k = 0; k < NTB; ++k) {
        if (tid < 128) {
            const int i0 = tid * 4;
            float4 r = ((const float4*)Rc[cur])[tid];
            *(float4*)(Rbuf + ((size_t)b * NTB + k) * NS + i0) = r;
            float4 s = *(const float4*)&S_l[k * NS + i0];
            float4 rp = (i0 >= TB) ? *(const float4*)&Rc[cur][i0 - TB]
                                   : make_float4(0.f, 0.f, 0.f, 0.f);
            float4 nv = make_float4(s.x + rp.x, s.y + rp.y, s.z + rp.z, s.w + rp.w);
            *(float4*)&Rc[cur ^ 1][i0] = nv;
        }
        __syncthreads();
        cur ^= 1;
    }
}

// ---------------------------------------------------------------------------
// corr (MFMA): y[b,t,p] -= sum_j qT[p][j] * s[b, t-1-j]
// ---------------------------------------------------------------------------
__global__ void __launch_bounds__(256) corr_kernel(
    const float* __restrict__ sbuf, const unsigned short* __restrict__ qT,
    float* __restrict__ y) {
    __shared__ float s_l[NS + TB];
    __shared__ unsigned short Qm[PO * LDC];
    __shared__ unsigned short Sw[TB * LDU];
    const int blk = blockIdx.x, b = blockIdx.y, tid = threadIdx.x;
    const int t0 = blk * TB;
    const int lane = tid & 63, w = tid >> 6;
    for (int idx = tid; idx < NS + TB; idx += 256) {
        const int t = t0 - NS + idx;
        s_l[idx] = (t >= 0) ? sbuf[(size_t)b * SEQ + t] : 0.f;
    }
    floatx4 acc[4];
#pragma unroll
    for (int nt = 0; nt < 4; ++nt) acc[nt] = (floatx4){0.f, 0.f, 0.f, 0.f};
    __syncthreads();

    for (int ch = 0; ch < NCH; ++ch) {
        const int r = tid >> 2, c0 = (tid & 3) * 16;
        {
            const uint4* qs = (const uint4*)(qT + (size_t)r * NS + ch * CH + c0);
            uint4 v0 = qs[0], v1 = qs[1];
            *(uint4*)&Qm[r * LDC + c0]     = v0;
            *(uint4*)&Qm[r * LDC + c0 + 8] = v1;
        }
        {
            unsigned short tmp[16];
            const int base = 511 + r - ch * CH - c0;
#pragma unroll
            for (int jj = 0; jj < 16; ++jj) tmp[jj] = f2bf(s_l[base - jj]);
            *(uint4*)&Sw[r * LDU + c0]     = *(uint4*)&tmp[0];
            *(uint4*)&Sw[r * LDU + c0 + 8] = *(uint4*)&tmp[8];
        }
        __syncthreads();
        const bf16x8 qa0 = *(const bf16x8*)&Qm[(w * 16 + (lane & 15)) * LDC + ((lane >> 4) * 8)];
        const bf16x8 qa1 = *(const bf16x8*)&Qm[(w * 16 + (lane & 15)) * LDC + 32 + ((lane >> 4) * 8)];
#pragma unroll
        for (int nt = 0; nt < 4; ++nt) {
            const int t = nt * 16 + (lane & 15);
            bf16x8 s0 = *(const bf16x8*)&Sw[t * LDU + ((lane >> 4) * 8)];
            bf16x8 s1 = *(const bf16x8*)&Sw[t * LDU + 32 + ((lane >> 4) * 8)];
            acc[nt] = __builtin_amdgcn_mfma_f32_16x16x32_bf16(qa0, s0, acc[nt], 0, 0, 0);
            acc[nt] = __builtin_amdgcn_mfma_f32_16x16x32_bf16(qa1, s1, acc[nt], 0, 0, 0);
        }
        __syncthreads();
    }
#pragma unroll
    for (int nt = 0; nt < 4; ++nt) {
        const int t = nt * 16 + (lane & 15);
        const int p0 = w * 16 + ((lane >> 4) * 4);
        float* yp = y + ((size_t)b * SEQ + t0 + t) * PO + p0;
        floatx4 old = *(const floatx4*)yp;
        *(floatx4*)yp = old - acc[nt];
    }
}

// ---------------------------------------------------------------------------
extern "C" void kernel_launch(void* const* d_in, const int* in_sizes, int n_in,
                              void* d_out, int out_size, void* d_ws,
                              size_t ws_size, hipStream_t stream) {
    const float* u  = (const float*)d_in[0];
    const float* a  = (const float*)d_in[1];
    const float* B  = (const float*)d_in[2];
    const float* Cm = (const float*)d_in[3];
    const float* Dm = (const float*)d_in[4];
    float* y = (float*)d_out;

    char* ws = (char*)d_ws;
    unsigned short* Bws = (unsigned short*)ws;                  ws += NS * MI * 2;
    unsigned short* Cws = (unsigned short*)ws;                  ws += PO * NS * 2;
    unsigned short* Dws = (unsigned short*)ws;                  ws += PO * MI * 2;
    unsigned short* qTw = (unsigned short*)ws;                  ws += PO * NS * 2;
    float* Sbuf = (float*)ws;                                   ws += (size_t)NB * NTB * NS * 4;
    float* Rbuf = (float*)ws;                                   ws += (size_t)NB * NTB * NS * 4;
    float* fbuf = (float*)ws;                                   ws += (size_t)NB * SEQ * 4;
    float* sbuf = (float*)ws;                                   ws += (size_t)NB * SEQ * 4;
    float* hbuf = (float*)ws;                                   // 2048 floats

    prep_kernel<<<dim3(272), dim3(256), 0, stream>>>(B, Cm, Dm, Bws, Cws, Dws);
    himp_kernel<<<dim3(1), dim3(1024), 0, stream>>>(a, hbuf);
    kq_kernel<<<dim3(NS), dim3(PO), 0, stream>>>(Cm, a, qTw);
    tile_kernel<0><<<dim3(NTB, NB), dim3(256), 0, stream>>>(
        u, Bws, Cws, Dws, nullptr, Sbuf, nullptr, nullptr);
    scan_kernel<<<dim3(NB), dim3(256), 0, stream>>>(Sbuf, Rbuf);
    tile_kernel<1><<<dim3(NTB, NB), dim3(256), 0, stream>>>(
        u, Bws, Cws, Dws, Rbuf, nullptr, fbuf, y);
    sconv_kernel<<<dim3(NTB, NB), dim3(256), 0, stream>>>(fbuf, hbuf, sbuf);
    corr_kernel<<<dim3(NTB, NB), dim3(256), 0, stream>>>(sbuf, qTw, y);
}